// Round 3
// baseline (366.046 us; speedup 1.0000x reference)
//
#include <hip/hip_runtime.h>
#include <cmath>

#define NB 16
#define MM 4096
#define MP1 4097
#define DD 512
#define LSEQ 196
#define NRB 65              // row-blocks of 64 rows
#define PSH (32 * 16 * 512) // ushorts per B hi-plane (512 KB)
#define MARGIN 0.05f
#define CANDMAX 128

typedef float f32x4 __attribute__((ext_vector_type(4)));
typedef short bf16x8 __attribute__((ext_vector_type(8)));
typedef unsigned short u16x8 __attribute__((ext_vector_type(8)));

static __device__ __forceinline__ unsigned short bf16_rne(float x) {
  union { float f; unsigned u; } c; c.f = x;
  unsigned u = c.u;
  u += 0x7fffu + ((u >> 16) & 1u);
  return (unsigned short)(u >> 16);
}
static __device__ __forceinline__ float sig_prec(float v) { return 1.0f / (1.0f + expf(-v)); }
static __device__ __forceinline__ float sig_fast(float v) { return 1.0f / (1.0f + __expf(-v)); }
static __device__ __forceinline__ float tanh_fast(float v) { return fmaf(2.0f, sig_fast(2.0f * v), -1.0f); }

// ---- pack Wv,Wu hi-bf16 planes in MFMA frag order --------------------------
// frag addr (ushorts): mat*PSH + (ctg*16 + ksg)*512 + lane*8
// element: W[k][col], col = ctg*16 + (l&15), k = ksg*32 + (l>>4)*8 + i
__global__ __launch_bounds__(256) void k_packW(const float* __restrict__ Wv,
                                               const float* __restrict__ Wu,
                                               unsigned short* __restrict__ Bp) {
  const int gid = blockIdx.x * 256 + threadIdx.x;  // 65536
  const int l = gid & 63;
  const int ksg = (gid >> 6) & 15;
  const int ctg = (gid >> 10) & 31;
  const int mat = gid >> 15;
  const float* W = mat ? Wu : Wv;
  const int col = ctg * 16 + (l & 15);
  const int kb = ksg * 32 + (l >> 4) * 8;
  u16x8 hi;
#pragma unroll
  for (int i = 0; i < 8; ++i) hi[i] = bf16_rne(W[(size_t)(kb + i) * DD + col]);
  *(u16x8*)(Bp + (size_t)mat * PSH + ((size_t)(ctg * 16 + ksg)) * 512 + l * 8) = hi;
}

// ---- pack feat (+cls, +zero pad) hi-bf16, tile-fragment-ordered ------------
// layout: Ah[((b*NRB+rb)*4 + kc)*8192 + (ks*4+rt)*512 + l*8]  (ushorts)
// element: row = rb*64 + rt*16 + (l&15), k = kc*128 + ks*32 + (l>>4)*8 + i
__global__ __launch_bounds__(256) void k_packA(const float* __restrict__ x,
                                               const float* __restrict__ feat_mem,
                                               unsigned short* __restrict__ Ah) {
  const int b = blockIdx.y, rb = blockIdx.x;
  const int kc = threadIdx.x >> 6, l = threadIdx.x & 63;
  unsigned short* dst = Ah + (((size_t)b * NRB + rb) * 4 + kc) * 8192;
#pragma unroll
  for (int f = 0; f < 16; ++f) {
    const int ks = f >> 2, rt = f & 3;
    const int grow = rb * 64 + rt * 16 + (l & 15);
    const int k = kc * 128 + ks * 32 + (l >> 4) * 8;
    float v[8] = {0.f, 0.f, 0.f, 0.f, 0.f, 0.f, 0.f, 0.f};
    if (grow <= MM) {
      const float* src = (grow < MM) ? feat_mem + ((size_t)b * MM + grow) * DD + k
                                     : x + (size_t)b * LSEQ * DD + k;
      const float4 t0 = ((const float4*)src)[0];
      const float4 t1 = ((const float4*)src)[1];
      v[0] = t0.x; v[1] = t0.y; v[2] = t0.z; v[3] = t0.w;
      v[4] = t1.x; v[5] = t1.y; v[6] = t1.z; v[7] = t1.w;
    }
    u16x8 hi;
#pragma unroll
    for (int i = 0; i < 8; ++i) hi[i] = bf16_rne(v[i]);
    *(u16x8*)(dst + f * 512 + l * 8) = hi;
  }
}

// ---- cheap logits: 1-term bf16 MFMA, 64 rows x 128 cols per block ----------
__global__ __launch_bounds__(256, 3) void k_scores(
    const unsigned short* __restrict__ Ah, const unsigned short* __restrict__ Bp,
    const float* __restrict__ bv, const float* __restrict__ bu,
    const float* __restrict__ Ww, float* __restrict__ logits) {
  const int rb = blockIdx.x, colb = blockIdx.y, b = blockIdx.z;
  const int tid = threadIdx.x, wave = tid >> 6, l = tid & 63;
  __shared__ __align__(16) unsigned short Alds[2][8192];  // 2 x 16 KB
  __shared__ float sred[4][64];

  const unsigned short* Abase = Ah + (((size_t)b * NRB + rb) * 4) * 8192;

  f32x4 accv[4][2], accu[4][2];
#pragma unroll
  for (int i = 0; i < 4; ++i)
#pragma unroll
    for (int j = 0; j < 2; ++j) {
      accv[i][j] = (f32x4){0.f, 0.f, 0.f, 0.f};
      accu[i][j] = (f32x4){0.f, 0.f, 0.f, 0.f};
    }

#define STAGE(kc, buf)                                                              \
  {                                                                                 \
    _Pragma("unroll")                                                               \
    for (int r = 0; r < 4; ++r) {                                                   \
      const unsigned short* g = Abase + (kc) * 8192 + r * 2048 + tid * 8;           \
      __builtin_amdgcn_global_load_lds(                                             \
          (const __attribute__((address_space(1))) void*)g,                         \
          (__attribute__((address_space(3))) void*)&Alds[(buf)][r * 2048 + tid * 8],\
          16, 0, 0);                                                                \
    }                                                                               \
  }

  STAGE(0, 0);
  __syncthreads();
  for (int kc = 0; kc < 4; ++kc) {
    if (kc < 3) STAGE(kc + 1, (kc + 1) & 1);
    const unsigned short* Ab = Alds[kc & 1];
#pragma unroll
    for (int ks = 0; ks < 4; ++ks) {
      bf16x8 hiA[4];
#pragma unroll
      for (int rt = 0; rt < 4; ++rt)
        hiA[rt] = *(const bf16x8*)(Ab + (ks * 4 + rt) * 512 + l * 8);
      const int ksg = kc * 4 + ks;
#pragma unroll
      for (int ct = 0; ct < 2; ++ct) {
        const int ctg = colb * 8 + wave * 2 + ct;
        const unsigned short* fb = Bp + ((size_t)(ctg * 16 + ksg)) * 512 + l * 8;
        const bf16x8 hv = *(const bf16x8*)fb;
        const bf16x8 hu = *(const bf16x8*)(fb + PSH);
#pragma unroll
        for (int rt = 0; rt < 4; ++rt) {
          accv[rt][ct] = __builtin_amdgcn_mfma_f32_16x16x32_bf16(hiA[rt], hv, accv[rt][ct], 0, 0, 0);
          accu[rt][ct] = __builtin_amdgcn_mfma_f32_16x16x32_bf16(hiA[rt], hu, accu[rt][ct], 0, 0, 0);
        }
      }
    }
    __syncthreads();
  }
#undef STAGE

  // epilogue: partial logit over this block's 128 cols
  float prow[4][4];
#pragma unroll
  for (int i = 0; i < 4; ++i)
#pragma unroll
    for (int j = 0; j < 4; ++j) prow[i][j] = 0.f;
#pragma unroll
  for (int ct = 0; ct < 2; ++ct) {
    const int col = colb * 128 + wave * 32 + ct * 16 + (l & 15);
    const float bvc = bv[col], buc = bu[col], wwc = Ww[col];
#pragma unroll
    for (int rt = 0; rt < 4; ++rt)
#pragma unroll
      for (int r = 0; r < 4; ++r) {
        const float vv = tanh_fast(accv[rt][ct][r] + bvc);
        const float uu = sig_fast(accu[rt][ct][r] + buc);
        prow[rt][r] = fmaf(vv * uu, wwc, prow[rt][r]);
      }
  }
#pragma unroll
  for (int off = 1; off < 16; off <<= 1)
#pragma unroll
    for (int rt = 0; rt < 4; ++rt)
#pragma unroll
      for (int r = 0; r < 4; ++r) prow[rt][r] += __shfl_xor(prow[rt][r], off, 64);

  if ((l & 15) == 0) {
#pragma unroll
    for (int rt = 0; rt < 4; ++rt)
#pragma unroll
      for (int r = 0; r < 4; ++r) sred[wave][rt * 16 + (l >> 4) * 4 + r] = prow[rt][r];
  }
  __syncthreads();
  if (tid < 64) {
    const float s = sred[0][tid] + sred[1][tid] + sred[2][tid] + sred[3][tid];
    const int row = rb * 64 + tid;
    if (row < MP1) atomicAdd(&logits[(size_t)b * MP1 + row], s);
  }
}

// ---- z = sum_rows sigmoid(logit+bw)*feat -----------------------------------
__global__ __launch_bounds__(256) void k_z(const float* __restrict__ x,
                                           const float* __restrict__ feat_mem,
                                           const float* __restrict__ logits,
                                           const float* __restrict__ bw,
                                           float* __restrict__ zacc) {
  const int b = blockIdx.y;
  const int rc = blockIdx.x >> 2;
  const int dc = blockIdx.x & 3;
  const int t = threadIdx.x;
  const int rpar = t >> 5;
  const int d = dc * 128 + (t & 31) * 4;
  const int rbeg = rc * 512;
  const int rend = (rc == 7) ? MP1 : rc * 512 + 512;
  const float bw0 = bw[0];
  float4 acc = make_float4(0.f, 0.f, 0.f, 0.f);
  for (int r = rbeg + rpar; r < rend; r += 8) {
    const float s = sig_fast(logits[(size_t)b * MP1 + r] + bw0);
    const float* src = (r < MM) ? feat_mem + ((size_t)b * MM + r) * DD
                                : x + (size_t)b * LSEQ * DD;
    const float4 f = *(const float4*)(src + d);
    acc.x = fmaf(s, f.x, acc.x);
    acc.y = fmaf(s, f.y, acc.y);
    acc.z = fmaf(s, f.z, acc.z);
    acc.w = fmaf(s, f.w, acc.w);
  }
  __shared__ float4 red[256];
  red[t] = acc;
  __syncthreads();
  if (t < 32) {
    float4 s = red[t];
#pragma unroll
    for (int j = 1; j < 8; ++j) {
      const float4 o = red[t + 32 * j];
      s.x += o.x; s.y += o.y; s.z += o.z; s.w += o.w;
    }
    atomicAdd(&zacc[(size_t)b * DD + d + 0], s.x);
    atomicAdd(&zacc[(size_t)b * DD + d + 1], s.y);
    atomicAdd(&zacc[(size_t)b * DD + d + 2], s.z);
    atomicAdd(&zacc[(size_t)b * DD + d + 3], s.w);
  }
}

// ---- candidate selection: rows with cheap logit <= min + MARGIN ------------
__global__ __launch_bounds__(256) void k_cand(const float* __restrict__ logits,
                                              int* __restrict__ cand,
                                              int* __restrict__ cnt) {
  const int b = blockIdx.x, tid = threadIdx.x;
  __shared__ float sv[256];
  __shared__ int scnt;
  float m = INFINITY;
  for (int i = tid; i < MP1; i += 256) m = fminf(m, logits[(size_t)b * MP1 + i]);
  sv[tid] = m;
  __syncthreads();
  for (int s = 128; s >= 1; s >>= 1) {
    if (tid < s) sv[tid] = fminf(sv[tid], sv[tid + s]);
    __syncthreads();
  }
  const float minv = sv[0];
  if (tid == 0) scnt = 0;
  __syncthreads();
  for (int i = tid; i < MP1; i += 256) {
    if (logits[(size_t)b * MP1 + i] <= minv + MARGIN) {
      const int p = atomicAdd(&scnt, 1);
      if (p < CANDMAX) cand[b * CANDMAX + p] = i;
    }
  }
  __syncthreads();
  if (tid == 0) cnt[b] = (scnt < CANDMAX) ? scnt : CANDMAX;
}

// ---- exact fp32 score for candidate rows -----------------------------------
__global__ __launch_bounds__(256) void k_refine(
    const float* __restrict__ x, const float* __restrict__ feat_mem,
    const float* __restrict__ Wv, const float* __restrict__ bv,
    const float* __restrict__ Wu, const float* __restrict__ bu,
    const float* __restrict__ Ww, const float* __restrict__ bw,
    const int* __restrict__ cand, const int* __restrict__ cnt,
    float* __restrict__ candsc) {
  const int b = blockIdx.y, c = blockIdx.x;
  if (c >= cnt[b]) return;
  const int row = cand[b * CANDMAX + c];
  const int j = threadIdx.x;
  __shared__ __align__(16) float sfeat[DD];
  __shared__ float sred[256];
  const float* src = (row < MM) ? feat_mem + ((size_t)b * MM + row) * DD
                                : x + (size_t)b * LSEQ * DD;
  if (j < 128) ((float4*)sfeat)[j] = ((const float4*)src)[j];
  __syncthreads();
  float v0 = 0.f, u0 = 0.f, v1 = 0.f, u1 = 0.f;
  for (int k = 0; k < DD; ++k) {
    const float a = sfeat[k];
    v0 = fmaf(a, Wv[(size_t)k * DD + j], v0);
    u0 = fmaf(a, Wu[(size_t)k * DD + j], u0);
    v1 = fmaf(a, Wv[(size_t)k * DD + j + 256], v1);
    u1 = fmaf(a, Wu[(size_t)k * DD + j + 256], u1);
  }
  const float c0 = tanhf(v0 + bv[j]) * sig_prec(u0 + bu[j]) * Ww[j];
  const float c1 = tanhf(v1 + bv[j + 256]) * sig_prec(u1 + bu[j + 256]) * Ww[j + 256];
  sred[j] = c0 + c1;
  __syncthreads();
  for (int s = 128; s >= 1; s >>= 1) {
    if (j < s) sred[j] += sred[j + s];
    __syncthreads();
  }
  if (j == 0) candsc[b * CANDMAX + c] = sig_prec(sred[0] + bw[0]);
}

// ---- finalize: argmin over refined candidates + exact-rational argmax ------
__global__ __launch_bounds__(256) void k_finalize2(
    const int* __restrict__ cand, const float* __restrict__ candsc,
    const int* __restrict__ cnt, const int* __restrict__ freq_mem,
    const int* __restrict__ min_mem, const float* __restrict__ zacc,
    float* __restrict__ out_z, float* __restrict__ out_freq,
    float* __restrict__ out_min, int* __restrict__ rm_attn) {
  const int b = blockIdx.x, tid = threadIdx.x;
  __shared__ float sv[256];
  __shared__ int si[256];
  __shared__ int sn[256], sd[256], sj[256];
  __shared__ int s_attn, s_rm;

  const int n = cnt[b];
  float v = INFINITY;
  int idx = MP1;
  if (tid < n) { v = candsc[b * CANDMAX + tid]; idx = cand[b * CANDMAX + tid]; }
  sv[tid] = v; si[tid] = idx;
  __syncthreads();
  for (int s = 128; s >= 1; s >>= 1) {
    if (tid < s) {
      const float v2 = sv[tid + s]; const int i2 = si[tid + s];
      if (v2 < sv[tid] || (v2 == sv[tid] && i2 < si[tid])) { sv[tid] = v2; si[tid] = i2; }
    }
    __syncthreads();
  }
  if (tid == 0) s_attn = si[0];
  __syncthreads();
  const int attn = s_attn;

  int bn = -1, bd = 1, bj = 0;
  for (int i = tid; i < MP1; i += 256) {
    int num, den;
    if (i < MM) {
      den = freq_mem[(size_t)b * MM + i] + 1;
      num = min_mem[(size_t)b * MM + i] + (i == attn ? 1 : 0);
      if (den <= 5) num = 0;
    } else { den = 1; num = 0; }
    if (num * bd > bn * den) { bn = num; bd = den; bj = i; }
  }
  sn[tid] = bn; sd[tid] = bd; sj[tid] = bj;
  __syncthreads();
  for (int s = 128; s >= 1; s >>= 1) {
    if (tid < s) {
      const int n2 = sn[tid + s], d2 = sd[tid + s], j2 = sj[tid + s];
      const int lft = n2 * sd[tid], rgt = sn[tid] * d2;
      if (lft > rgt || (lft == rgt && j2 < sj[tid])) { sn[tid] = n2; sd[tid] = d2; sj[tid] = j2; }
    }
    __syncthreads();
  }
  if (tid == 0) { s_rm = sj[0]; rm_attn[b * 2] = attn; rm_attn[b * 2 + 1] = sj[0]; }
  __syncthreads();
  const int rm = s_rm;

  for (int i = tid; i < MM; i += 256) {
    const int src = (i < rm) ? i : i + 1;
    int fv, mv;
    if (src < MM) {
      fv = freq_mem[(size_t)b * MM + src] + 1;
      mv = min_mem[(size_t)b * MM + src] + (src == attn ? 1 : 0);
    } else {
      fv = 1; mv = (attn == MM) ? 1 : 0;
    }
    out_freq[(size_t)b * MM + i] = (float)fv;
    out_min[(size_t)b * MM + i] = (float)mv;
  }
  for (int d = tid; d < DD; d += 256) out_z[(size_t)b * DD + d] = zacc[(size_t)b * DD + d];
}

// ---- feat_out gather (verified R1/R2) --------------------------------------
__global__ __launch_bounds__(256) void k_gather(
    const float* __restrict__ feat_mem, const float* __restrict__ x,
    const int* __restrict__ rm_attn, float* __restrict__ out_feat) {
  const int b = blockIdx.y;
  const int rm = rm_attn[b * 2 + 1];
  const int row = blockIdx.x * 4 + (threadIdx.x >> 6);
  const int lane = threadIdx.x & 63;
  const int src = (row < rm) ? row : row + 1;
  const float* sp = (src < MM) ? (feat_mem + ((size_t)b * MM + src) * DD)
                               : (x + (size_t)b * LSEQ * DD);
  float* dp = out_feat + ((size_t)b * MM + row) * DD;
  const float4 v0 = reinterpret_cast<const float4*>(sp)[lane];
  const float4 v1 = reinterpret_cast<const float4*>(sp)[lane + 64];
  reinterpret_cast<float4*>(dp)[lane] = v0;
  reinterpret_cast<float4*>(dp)[lane + 64] = v1;
}

extern "C" void kernel_launch(void* const* d_in, const int* in_sizes, int n_in,
                              void* d_out, int out_size, void* d_ws, size_t ws_size,
                              hipStream_t stream) {
  const float* x        = (const float*)d_in[0];
  const float* feat_mem = (const float*)d_in[1];
  const int*   freq_mem = (const int*)d_in[2];
  const int*   min_mem  = (const int*)d_in[3];
  const float* Wv       = (const float*)d_in[4];
  const float* bv       = (const float*)d_in[5];
  const float* Wu       = (const float*)d_in[6];
  const float* bu       = (const float*)d_in[7];
  const float* Ww       = (const float*)d_in[8];
  const float* bw       = (const float*)d_in[9];

  float* ws     = (float*)d_ws;
  float* logits = ws;                               // 65552
  float* zacc   = ws + NB * MP1;                    // 8192
  float* candsc = zacc + NB * DD;                   // 2048
  int*   cand   = (int*)(candsc + NB * CANDMAX);    // 2048
  int*   cnt    = cand + NB * CANDMAX;              // 16
  int*   rm_attn = cnt + NB;                        // 32
  unsigned short* Bp = (unsigned short*)(rm_attn + 32);  // 1 MB

  float* out_z    = (float*)d_out;
  float* out_feat = out_z + NB * DD;
  float* out_freq = out_feat + (size_t)NB * MM * DD;
  float* out_min  = out_freq + (size_t)NB * MM;

  // A-hi planes live in the (not-yet-written) out_feat region: 68 MB of 134 MB.
  unsigned short* Ah = (unsigned short*)out_feat;

  hipMemsetAsync(logits, 0, (NB * MP1 + NB * DD) * sizeof(float), stream);  // logits+zacc
  hipMemsetAsync(cnt, 0, NB * sizeof(int), stream);

  k_packW<<<dim3(256), dim3(256), 0, stream>>>(Wv, Wu, Bp);
  k_packA<<<dim3(NRB, NB), dim3(256), 0, stream>>>(x, feat_mem, Ah);
  k_scores<<<dim3(NRB, 4, NB), dim3(256), 0, stream>>>(Ah, Bp, bv, bu, Ww, logits);
  k_z<<<dim3(32, NB), dim3(256), 0, stream>>>(x, feat_mem, logits, bw, zacc);
  k_cand<<<dim3(NB), dim3(256), 0, stream>>>(logits, cand, cnt);
  k_refine<<<dim3(CANDMAX, NB), dim3(256), 0, stream>>>(x, feat_mem, Wv, bv, Wu, bu, Ww, bw,
                                                        cand, cnt, candsc);
  k_finalize2<<<dim3(NB), dim3(256), 0, stream>>>(cand, candsc, cnt, freq_mem, min_mem, zacc,
                                                  out_z, out_freq, out_min, rm_attn);
  k_gather<<<dim3(MM / 4, NB), dim3(256), 0, stream>>>(feat_mem, x, rm_attn, out_feat);
}

// Round 4
// 263.314 us; speedup vs baseline: 1.3901x; 1.3901x over previous
//
#include <hip/hip_runtime.h>
#include <cmath>

#define NB 16
#define MM 4096
#define MP1 4097
#define DD 512
#define LSEQ 196
#define NRB 65              // row-blocks of 64 rows
#define PSH (32 * 16 * 512) // ushorts per B hi-plane (512 KB)
#define MARGIN 0.05f
#define CANDMAX 128

typedef float f32x4 __attribute__((ext_vector_type(4)));
typedef short bf16x8 __attribute__((ext_vector_type(8)));
typedef unsigned short u16x8 __attribute__((ext_vector_type(8)));

static __device__ __forceinline__ unsigned short bf16_rne(float x) {
  union { float f; unsigned u; } c; c.f = x;
  unsigned u = c.u;
  u += 0x7fffu + ((u >> 16) & 1u);
  return (unsigned short)(u >> 16);
}
static __device__ __forceinline__ float sig_prec(float v) { return 1.0f / (1.0f + expf(-v)); }
static __device__ __forceinline__ float sig_fast(float v) { return 1.0f / (1.0f + __expf(-v)); }
static __device__ __forceinline__ float tanh_fast(float v) { return fmaf(2.0f, sig_fast(2.0f * v), -1.0f); }

// ---- pack Wv,Wu hi-bf16 planes in MFMA frag order --------------------------
__global__ __launch_bounds__(256) void k_packW(const float* __restrict__ Wv,
                                               const float* __restrict__ Wu,
                                               unsigned short* __restrict__ Bp) {
  const int gid = blockIdx.x * 256 + threadIdx.x;  // 65536
  const int l = gid & 63;
  const int ksg = (gid >> 6) & 15;
  const int ctg = (gid >> 10) & 31;
  const int mat = gid >> 15;
  const float* W = mat ? Wu : Wv;
  const int col = ctg * 16 + (l & 15);
  const int kb = ksg * 32 + (l >> 4) * 8;
  u16x8 hi;
#pragma unroll
  for (int i = 0; i < 8; ++i) hi[i] = bf16_rne(W[(size_t)(kb + i) * DD + col]);
  *(u16x8*)(Bp + (size_t)mat * PSH + ((size_t)(ctg * 16 + ksg)) * 512 + l * 8) = hi;
}

// ---- pack feat (+cls, +zero pad) hi-bf16, tile-fragment-ordered ------------
__global__ __launch_bounds__(256) void k_packA(const float* __restrict__ x,
                                               const float* __restrict__ feat_mem,
                                               unsigned short* __restrict__ Ah) {
  const int b = blockIdx.y, rb = blockIdx.x;
  const int kc = threadIdx.x >> 6, l = threadIdx.x & 63;
  unsigned short* dst = Ah + (((size_t)b * NRB + rb) * 4 + kc) * 8192;
#pragma unroll
  for (int f = 0; f < 16; ++f) {
    const int ks = f >> 2, rt = f & 3;
    const int grow = rb * 64 + rt * 16 + (l & 15);
    const int k = kc * 128 + ks * 32 + (l >> 4) * 8;
    float v[8] = {0.f, 0.f, 0.f, 0.f, 0.f, 0.f, 0.f, 0.f};
    if (grow <= MM) {
      const float* src = (grow < MM) ? feat_mem + ((size_t)b * MM + grow) * DD + k
                                     : x + (size_t)b * LSEQ * DD + k;
      const float4 t0 = ((const float4*)src)[0];
      const float4 t1 = ((const float4*)src)[1];
      v[0] = t0.x; v[1] = t0.y; v[2] = t0.z; v[3] = t0.w;
      v[4] = t1.x; v[5] = t1.y; v[6] = t1.z; v[7] = t1.w;
    }
    u16x8 hi;
#pragma unroll
    for (int i = 0; i < 8; ++i) hi[i] = bf16_rne(v[i]);
    *(u16x8*)(dst + f * 512 + l * 8) = hi;
  }
}

// ---- cheap logits: 1-term bf16 MFMA, 64 rows x 128 cols per block ----------
__global__ __launch_bounds__(256, 3) void k_scores(
    const unsigned short* __restrict__ Ah, const unsigned short* __restrict__ Bp,
    const float* __restrict__ bv, const float* __restrict__ bu,
    const float* __restrict__ Ww, float* __restrict__ logits) {
  const int rb = blockIdx.x, colb = blockIdx.y, b = blockIdx.z;
  const int tid = threadIdx.x, wave = tid >> 6, l = tid & 63;
  __shared__ __align__(16) unsigned short Alds[2][8192];  // 2 x 16 KB
  __shared__ float sred[4][64];

  const unsigned short* Abase = Ah + (((size_t)b * NRB + rb) * 4) * 8192;

  f32x4 accv[4][2], accu[4][2];
#pragma unroll
  for (int i = 0; i < 4; ++i)
#pragma unroll
    for (int j = 0; j < 2; ++j) {
      accv[i][j] = (f32x4){0.f, 0.f, 0.f, 0.f};
      accu[i][j] = (f32x4){0.f, 0.f, 0.f, 0.f};
    }

#define STAGE(kc, buf)                                                              \
  {                                                                                 \
    _Pragma("unroll")                                                               \
    for (int r = 0; r < 4; ++r) {                                                   \
      const unsigned short* g = Abase + (kc) * 8192 + r * 2048 + tid * 8;           \
      __builtin_amdgcn_global_load_lds(                                             \
          (const __attribute__((address_space(1))) void*)g,                         \
          (__attribute__((address_space(3))) void*)&Alds[(buf)][r * 2048 + tid * 8],\
          16, 0, 0);                                                                \
    }                                                                               \
  }

  STAGE(0, 0);
  __syncthreads();
  for (int kc = 0; kc < 4; ++kc) {
    if (kc < 3) STAGE(kc + 1, (kc + 1) & 1);
    const unsigned short* Ab = Alds[kc & 1];
#pragma unroll
    for (int ks = 0; ks < 4; ++ks) {
      bf16x8 hiA[4];
#pragma unroll
      for (int rt = 0; rt < 4; ++rt)
        hiA[rt] = *(const bf16x8*)(Ab + (ks * 4 + rt) * 512 + l * 8);
      const int ksg = kc * 4 + ks;
#pragma unroll
      for (int ct = 0; ct < 2; ++ct) {
        const int ctg = colb * 8 + wave * 2 + ct;
        const unsigned short* fb = Bp + ((size_t)(ctg * 16 + ksg)) * 512 + l * 8;
        const bf16x8 hv = *(const bf16x8*)fb;
        const bf16x8 hu = *(const bf16x8*)(fb + PSH);
#pragma unroll
        for (int rt = 0; rt < 4; ++rt) {
          accv[rt][ct] = __builtin_amdgcn_mfma_f32_16x16x32_bf16(hiA[rt], hv, accv[rt][ct], 0, 0, 0);
          accu[rt][ct] = __builtin_amdgcn_mfma_f32_16x16x32_bf16(hiA[rt], hu, accu[rt][ct], 0, 0, 0);
        }
      }
    }
    __syncthreads();
  }
#undef STAGE

  float prow[4][4];
#pragma unroll
  for (int i = 0; i < 4; ++i)
#pragma unroll
    for (int j = 0; j < 4; ++j) prow[i][j] = 0.f;
#pragma unroll
  for (int ct = 0; ct < 2; ++ct) {
    const int col = colb * 128 + wave * 32 + ct * 16 + (l & 15);
    const float bvc = bv[col], buc = bu[col], wwc = Ww[col];
#pragma unroll
    for (int rt = 0; rt < 4; ++rt)
#pragma unroll
      for (int r = 0; r < 4; ++r) {
        const float vv = tanh_fast(accv[rt][ct][r] + bvc);
        const float uu = sig_fast(accu[rt][ct][r] + buc);
        prow[rt][r] = fmaf(vv * uu, wwc, prow[rt][r]);
      }
  }
#pragma unroll
  for (int off = 1; off < 16; off <<= 1)
#pragma unroll
    for (int rt = 0; rt < 4; ++rt)
#pragma unroll
      for (int r = 0; r < 4; ++r) prow[rt][r] += __shfl_xor(prow[rt][r], off, 64);

  if ((l & 15) == 0) {
#pragma unroll
    for (int rt = 0; rt < 4; ++rt)
#pragma unroll
      for (int r = 0; r < 4; ++r) sred[wave][rt * 16 + (l >> 4) * 4 + r] = prow[rt][r];
  }
  __syncthreads();
  if (tid < 64) {
    const float s = sred[0][tid] + sred[1][tid] + sred[2][tid] + sred[3][tid];
    const int row = rb * 64 + tid;
    if (row < MP1) atomicAdd(&logits[(size_t)b * MP1 + row], s);
  }
}

// ---- z = sum_rows sigmoid(logit+bw)*feat -----------------------------------
__global__ __launch_bounds__(256) void k_z(const float* __restrict__ x,
                                           const float* __restrict__ feat_mem,
                                           const float* __restrict__ logits,
                                           const float* __restrict__ bw,
                                           float* __restrict__ zacc) {
  const int b = blockIdx.y;
  const int rc = blockIdx.x >> 2;
  const int dc = blockIdx.x & 3;
  const int t = threadIdx.x;
  const int rpar = t >> 5;
  const int d = dc * 128 + (t & 31) * 4;
  const int rbeg = rc * 512;
  const int rend = (rc == 7) ? MP1 : rc * 512 + 512;
  const float bw0 = bw[0];
  float4 acc = make_float4(0.f, 0.f, 0.f, 0.f);
  for (int r = rbeg + rpar; r < rend; r += 8) {
    const float s = sig_fast(logits[(size_t)b * MP1 + r] + bw0);
    const float* src = (r < MM) ? feat_mem + ((size_t)b * MM + r) * DD
                                : x + (size_t)b * LSEQ * DD;
    const float4 f = *(const float4*)(src + d);
    acc.x = fmaf(s, f.x, acc.x);
    acc.y = fmaf(s, f.y, acc.y);
    acc.z = fmaf(s, f.z, acc.z);
    acc.w = fmaf(s, f.w, acc.w);
  }
  __shared__ float4 red[256];
  red[t] = acc;
  __syncthreads();
  if (t < 32) {
    float4 s = red[t];
#pragma unroll
    for (int j = 1; j < 8; ++j) {
      const float4 o = red[t + 32 * j];
      s.x += o.x; s.y += o.y; s.z += o.z; s.w += o.w;
    }
    atomicAdd(&zacc[(size_t)b * DD + d + 0], s.x);
    atomicAdd(&zacc[(size_t)b * DD + d + 1], s.y);
    atomicAdd(&zacc[(size_t)b * DD + d + 2], s.z);
    atomicAdd(&zacc[(size_t)b * DD + d + 3], s.w);
  }
}

// ---- candidate selection: rows with cheap logit <= min + MARGIN ------------
__global__ __launch_bounds__(256) void k_cand(const float* __restrict__ logits,
                                              int* __restrict__ cand,
                                              int* __restrict__ cnt) {
  const int b = blockIdx.x, tid = threadIdx.x;
  __shared__ float sv[256];
  __shared__ int scnt;
  float m = INFINITY;
  for (int i = tid; i < MP1; i += 256) m = fminf(m, logits[(size_t)b * MP1 + i]);
  sv[tid] = m;
  __syncthreads();
  for (int s = 128; s >= 1; s >>= 1) {
    if (tid < s) sv[tid] = fminf(sv[tid], sv[tid + s]);
    __syncthreads();
  }
  const float minv = sv[0];
  if (tid == 0) scnt = 0;
  __syncthreads();
  for (int i = tid; i < MP1; i += 256) {
    if (logits[(size_t)b * MP1 + i] <= minv + MARGIN) {
      const int p = atomicAdd(&scnt, 1);
      if (p < CANDMAX) cand[b * CANDMAX + p] = i;
    }
  }
  __syncthreads();
  if (tid == 0) cnt[b] = (scnt < CANDMAX) ? scnt : CANDMAX;
}

// ---- exact fp32 logit partials for candidate rows (col-block parallel) -----
// grid (8, CANDMAX, NB): block cb computes cols [cb*64, cb*64+64), writes
// candpart[(b*CANDMAX+c)*8 + cb]. 4 k-slices x 64 cols per block.
__global__ __launch_bounds__(256) void k_refine(
    const float* __restrict__ x, const float* __restrict__ feat_mem,
    const float* __restrict__ Wv, const float* __restrict__ bv,
    const float* __restrict__ Wu, const float* __restrict__ bu,
    const float* __restrict__ Ww,
    const int* __restrict__ cand, const int* __restrict__ cnt,
    float* __restrict__ candpart) {
  const int b = blockIdx.z, c = blockIdx.y, cb = blockIdx.x;
  if (c >= cnt[b]) return;
  const int row = cand[b * CANDMAX + c];
  const int tid = threadIdx.x;
  const int jl = tid & 63;   // column within col-block
  const int ks = tid >> 6;   // k-slice 0..3 (one per wave)
  const int col = cb * 64 + jl;
  __shared__ __align__(16) float sfeat[DD];
  __shared__ float sredv[4][64];
  __shared__ float sredu[4][64];
  const float* src = (row < MM) ? feat_mem + ((size_t)b * MM + row) * DD
                                : x + (size_t)b * LSEQ * DD;
  if (tid < 128) ((float4*)sfeat)[tid] = ((const float4*)src)[tid];
  __syncthreads();
  float v = 0.f, u = 0.f;
  const float* wvp = Wv + (size_t)(ks * 128) * DD + col;
  const float* wup = Wu + (size_t)(ks * 128) * DD + col;
#pragma unroll 8
  for (int k = 0; k < 128; ++k) {
    const float a = sfeat[ks * 128 + k];   // wave-uniform LDS broadcast
    v = fmaf(a, wvp[(size_t)k * DD], v);
    u = fmaf(a, wup[(size_t)k * DD], u);
  }
  sredv[ks][jl] = v;
  sredu[ks][jl] = u;
  __syncthreads();
  if (tid < 64) {
    const float vv = (sredv[0][jl] + sredv[1][jl]) + (sredv[2][jl] + sredv[3][jl]);
    const float uu = (sredu[0][jl] + sredu[1][jl]) + (sredu[2][jl] + sredu[3][jl]);
    float g = tanhf(vv + bv[col]) * sig_prec(uu + bu[col]) * Ww[col];
#pragma unroll
    for (int off = 1; off < 64; off <<= 1) g += __shfl_xor(g, off, 64);
    if (jl == 0) candpart[((size_t)b * CANDMAX + c) * 8 + cb] = g;
  }
}

// ---- finalize: argmin over refined candidate logits + exact-rational argmax -
__global__ __launch_bounds__(256) void k_finalize2(
    const int* __restrict__ cand, const float* __restrict__ candpart,
    const int* __restrict__ cnt, const int* __restrict__ freq_mem,
    const int* __restrict__ min_mem, const float* __restrict__ zacc,
    float* __restrict__ out_z, float* __restrict__ out_freq,
    float* __restrict__ out_min, int* __restrict__ rm_attn) {
  const int b = blockIdx.x, tid = threadIdx.x;
  __shared__ float sv[256];
  __shared__ int si[256];
  __shared__ int sn[256], sd[256], sj[256];
  __shared__ int s_attn, s_rm;

  const int n = cnt[b];
  float v = INFINITY;
  int idx = MP1;
  if (tid < n) {
    const float* p = candpart + ((size_t)b * CANDMAX + tid) * 8;
    v = ((p[0] + p[1]) + (p[2] + p[3])) + ((p[4] + p[5]) + (p[6] + p[7]));
    idx = cand[b * CANDMAX + tid];
  }
  sv[tid] = v; si[tid] = idx;
  __syncthreads();
  for (int s = 128; s >= 1; s >>= 1) {
    if (tid < s) {
      const float v2 = sv[tid + s]; const int i2 = si[tid + s];
      if (v2 < sv[tid] || (v2 == sv[tid] && i2 < si[tid])) { sv[tid] = v2; si[tid] = i2; }
    }
    __syncthreads();
  }
  if (tid == 0) s_attn = si[0];
  __syncthreads();
  const int attn = s_attn;

  int bn = -1, bd = 1, bj = 0;
  for (int i = tid; i < MP1; i += 256) {
    int num, den;
    if (i < MM) {
      den = freq_mem[(size_t)b * MM + i] + 1;
      num = min_mem[(size_t)b * MM + i] + (i == attn ? 1 : 0);
      if (den <= 5) num = 0;
    } else { den = 1; num = 0; }
    if (num * bd > bn * den) { bn = num; bd = den; bj = i; }
  }
  sn[tid] = bn; sd[tid] = bd; sj[tid] = bj;
  __syncthreads();
  for (int s = 128; s >= 1; s >>= 1) {
    if (tid < s) {
      const int n2 = sn[tid + s], d2 = sd[tid + s], j2 = sj[tid + s];
      const int lft = n2 * sd[tid], rgt = sn[tid] * d2;
      if (lft > rgt || (lft == rgt && j2 < sj[tid])) { sn[tid] = n2; sd[tid] = d2; sj[tid] = j2; }
    }
    __syncthreads();
  }
  if (tid == 0) { s_rm = sj[0]; rm_attn[b * 2] = attn; rm_attn[b * 2 + 1] = sj[0]; }
  __syncthreads();
  const int rm = s_rm;

  for (int i = tid; i < MM; i += 256) {
    const int src = (i < rm) ? i : i + 1;
    int fv, mv;
    if (src < MM) {
      fv = freq_mem[(size_t)b * MM + src] + 1;
      mv = min_mem[(size_t)b * MM + src] + (src == attn ? 1 : 0);
    } else {
      fv = 1; mv = (attn == MM) ? 1 : 0;
    }
    out_freq[(size_t)b * MM + i] = (float)fv;
    out_min[(size_t)b * MM + i] = (float)mv;
  }
  for (int d = tid; d < DD; d += 256) out_z[(size_t)b * DD + d] = zacc[(size_t)b * DD + d];
}

// ---- feat_out gather (verified R1-R3) ---------------------------------------
__global__ __launch_bounds__(256) void k_gather(
    const float* __restrict__ feat_mem, const float* __restrict__ x,
    const int* __restrict__ rm_attn, float* __restrict__ out_feat) {
  const int b = blockIdx.y;
  const int rm = rm_attn[b * 2 + 1];
  const int row = blockIdx.x * 4 + (threadIdx.x >> 6);
  const int lane = threadIdx.x & 63;
  const int src = (row < rm) ? row : row + 1;
  const float* sp = (src < MM) ? (feat_mem + ((size_t)b * MM + src) * DD)
                               : (x + (size_t)b * LSEQ * DD);
  float* dp = out_feat + ((size_t)b * MM + row) * DD;
  const float4 v0 = reinterpret_cast<const float4*>(sp)[lane];
  const float4 v1 = reinterpret_cast<const float4*>(sp)[lane + 64];
  reinterpret_cast<float4*>(dp)[lane] = v0;
  reinterpret_cast<float4*>(dp)[lane + 64] = v1;
}

extern "C" void kernel_launch(void* const* d_in, const int* in_sizes, int n_in,
                              void* d_out, int out_size, void* d_ws, size_t ws_size,
                              hipStream_t stream) {
  const float* x        = (const float*)d_in[0];
  const float* feat_mem = (const float*)d_in[1];
  const int*   freq_mem = (const int*)d_in[2];
  const int*   min_mem  = (const int*)d_in[3];
  const float* Wv       = (const float*)d_in[4];
  const float* bv       = (const float*)d_in[5];
  const float* Wu       = (const float*)d_in[6];
  const float* bu       = (const float*)d_in[7];
  const float* Ww       = (const float*)d_in[8];
  const float* bw       = (const float*)d_in[9];

  float* ws       = (float*)d_ws;
  float* logits   = ws;                                   // 65552
  float* zacc     = ws + NB * MP1;                        // 8192
  float* candpart = zacc + NB * DD;                       // 16384
  int*   cand     = (int*)(candpart + NB * CANDMAX * 8);  // 2048
  int*   cnt      = cand + NB * CANDMAX;                  // 16
  int*   rm_attn  = cnt + NB;                             // 32
  unsigned short* Bp = (unsigned short*)(rm_attn + 32);   // 1 MB

  float* out_z    = (float*)d_out;
  float* out_feat = out_z + NB * DD;
  float* out_freq = out_feat + (size_t)NB * MM * DD;
  float* out_min  = out_freq + (size_t)NB * MM;

  // A-hi planes live in the (not-yet-written) out_feat region: 68 MB of 134 MB.
  unsigned short* Ah = (unsigned short*)out_feat;

  hipMemsetAsync(logits, 0, (NB * MP1 + NB * DD) * sizeof(float), stream);  // logits+zacc
  hipMemsetAsync(cnt, 0, NB * sizeof(int), stream);

  k_packW<<<dim3(256), dim3(256), 0, stream>>>(Wv, Wu, Bp);
  k_packA<<<dim3(NRB, NB), dim3(256), 0, stream>>>(x, feat_mem, Ah);
  k_scores<<<dim3(NRB, 4, NB), dim3(256), 0, stream>>>(Ah, Bp, bv, bu, Ww, logits);
  k_z<<<dim3(32, NB), dim3(256), 0, stream>>>(x, feat_mem, logits, bw, zacc);
  k_cand<<<dim3(NB), dim3(256), 0, stream>>>(logits, cand, cnt);
  k_refine<<<dim3(8, CANDMAX, NB), dim3(256), 0, stream>>>(x, feat_mem, Wv, bv, Wu, bu, Ww,
                                                           cand, cnt, candpart);
  k_finalize2<<<dim3(NB), dim3(256), 0, stream>>>(cand, candpart, cnt, freq_mem, min_mem, zacc,
                                                  out_z, out_freq, out_min, rm_attn);
  k_gather<<<dim3(MM / 4, NB), dim3(256), 0, stream>>>(feat_mem, x, rm_attn, out_feat);
}